// Round 4
// baseline (960.642 us; speedup 1.0000x reference)
//
#include <hip/hip_runtime.h>
#include <hip/hip_bf16.h>

#define E_TOT   1600000
#define NN      50000
#define K1      176     // msg MLP input dim (2*64+32+16)
#define H1      128     // MSG_HID
#define HS2     136     // act row stride (ushorts), 272B, 16B aligned
#define SCAN_T  1024
#define SCAN_CH 49      // 49*1024 >= 50001

typedef __attribute__((ext_vector_type(8))) short bf16x8;
typedef __attribute__((ext_vector_type(4))) float f32x4;

__device__ __forceinline__ unsigned short f2bf(float x) {
  unsigned u = __builtin_bit_cast(unsigned, x);
  return (unsigned short)((u + 0x7FFFu + ((u >> 16) & 1u)) >> 16);   // RNE
}
__device__ __forceinline__ float silu_f(float x) { return x / (1.0f + __expf(-x)); }

__device__ __forceinline__ bf16x8 ldf8(const float* __restrict__ p) {
  float4 a = ((const float4*)p)[0];
  float4 b = ((const float4*)p)[1];
  bf16x8 r;
  r[0] = (short)f2bf(a.x); r[1] = (short)f2bf(a.y);
  r[2] = (short)f2bf(a.z); r[3] = (short)f2bf(a.w);
  r[4] = (short)f2bf(b.x); r[5] = (short)f2bf(b.y);
  r[6] = (short)f2bf(b.z); r[7] = (short)f2bf(b.w);
  return r;
}

// ---------------------------------------------------------------------------
// CSR build: histogram -> single-block scan -> scatter edge ids by dst.
// ---------------------------------------------------------------------------
__global__ void hist_k(const int* __restrict__ eidx, int* __restrict__ count) {
  int i = blockIdx.x * blockDim.x + threadIdx.x;
  int stride = gridDim.x * blockDim.x;
  for (; i < E_TOT; i += stride) atomicAdd(&count[eidx[E_TOT + i]], 1);
}

__global__ __launch_bounds__(SCAN_T) void scan_k(const int* __restrict__ count,
                                                 int* __restrict__ row_start,
                                                 int* __restrict__ cursor) {
  __shared__ int sm[SCAN_T];
  const int t = threadIdx.x;
  const int base = t * SCAN_CH;
  int s = 0;
  for (int i = 0; i < SCAN_CH; ++i) {
    int idx = base + i;
    s += (idx < NN) ? count[idx] : 0;
  }
  sm[t] = s;
  __syncthreads();
  for (int off = 1; off < SCAN_T; off <<= 1) {   // Hillis-Steele inclusive
    int v = (t >= off) ? sm[t - off] : 0;
    __syncthreads();
    sm[t] += v;
    __syncthreads();
  }
  int run = (t == 0) ? 0 : sm[t - 1];            // exclusive prefix
  for (int i = 0; i < SCAN_CH; ++i) {
    int idx = base + i;
    if (idx < NN) {
      row_start[idx] = run; cursor[idx] = run;
      run += count[idx];
    } else if (idx == NN) {
      row_start[NN] = run;
    }
  }
}

__global__ void scatter_k(const int* __restrict__ eidx, int* __restrict__ cursor,
                          int* __restrict__ eid) {
  int i = blockIdx.x * blockDim.x + threadIdx.x;
  int stride = gridDim.x * blockDim.x;
  for (; i < E_TOT; i += stride) {
    int d = eidx[E_TOT + i];
    int pos = atomicAdd(&cursor[d], 1);
    eid[pos] = i;
  }
}

// ---------------------------------------------------------------------------
// Edge kernel v4: one DST NODE per wave (barrier-free after weight staging).
// Per node: loop incoming edges in chunks of 32 (via CSR eid), run the 3-GEMM
// MLP chain, accumulate msg column sums + mov in registers (masked for pad
// rows), then ONE non-atomic store of msg_tot row + out_coord row. No atomics.
// Fragment convention (16x16x32 bf16): A elem j of lane l = A[l%16][(l/16)*8+j],
// B elem j = B[(l/16)*8+j][l%16] (same k-map => permutation-safe).
// C/D: col = lane&15, row = (lane>>4)*4 + reg   (HW-verified).
// ---------------------------------------------------------------------------
__global__ __launch_bounds__(512, 1) void egnn_edge(
    const float* __restrict__ node_feat, const float* __restrict__ coord,
    const float* __restrict__ edge_feat, const int* __restrict__ eidx,
    const int* __restrict__ row_start, const int* __restrict__ eid,
    const float* __restrict__ w1_msg, const float* __restrict__ w2_msg,
    const float* __restrict__ w1_mov, const float* __restrict__ w2_mov,
    float* __restrict__ msg_tot, float* __restrict__ out_coord)
{
  __shared__ unsigned short w1f[6*8*64*8];     // 48KB  [kb<6][nt<8][lane][8]
  __shared__ unsigned short w2f[4*4*64*8];     // 16KB
  __shared__ unsigned short w3f[2*4*64*8];     // 8KB
  __shared__ unsigned short act[8][32*HS2];    // 69.6KB, per-wave h/m (aliased)

  const int t = threadIdx.x;
  const int lane = t & 63;
  const int wv = t >> 6;

  // ---- stage weight fragments (once per block) ----
  for (int i = t; i < 6*8*64*8; i += 512) {
    int j = i & 7, l = (i >> 3) & 63, nt = (i >> 9) & 7, kb = i >> 12;
    int k = kb*32 + (l >> 4)*8 + j;
    w1f[i] = f2bf(k < K1 ? w1_msg[k*H1 + nt*16 + (l & 15)] : 0.0f);
  }
  for (int i = t; i < 4*4*64*8; i += 512) {
    int j = i & 7, l = (i >> 3) & 63, nt = (i >> 9) & 3, kb = i >> 11;
    w2f[i] = f2bf(w2_msg[(kb*32 + (l >> 4)*8 + j)*64 + nt*16 + (l & 15)]);
  }
  for (int i = t; i < 2*4*64*8; i += 512) {
    int j = i & 7, l = (i >> 3) & 63, nt = (i >> 9) & 3, kb = i >> 11;
    w3f[i] = f2bf(w1_mov[(kb*32 + (l >> 4)*8 + j)*64 + nt*16 + (l & 15)]);
  }

  const int cl = lane & 15;           // A row within 16-tile / C col
  const int g8 = (lane >> 4) * 8;     // k sub-offset
  const int orow4 = (lane >> 4) * 4;  // C row base within 16-tile
  float w2m_r[4];
  #pragma unroll
  for (int nt = 0; nt < 4; ++nt) w2m_r[nt] = w2_mov[nt*16 + cl];

  __syncthreads();                    // weights ready; no barriers after this

  unsigned short* const myact = &act[wv][0];
  const int NW = gridDim.x * 8;

  for (int n = blockIdx.x * 8 + wv; n < NN; n += NW) {
    const int rs  = row_start[n];
    const int re  = row_start[n + 1];
    const int deg = re - rs;
    const float cdx = coord[(size_t)n*3 + 0];
    const float cdy = coord[(size_t)n*3 + 1];
    const float cdz = coord[(size_t)n*3 + 2];
    float msg_part[4] = {0.f, 0.f, 0.f, 0.f};
    float movx = 0.f, movy = 0.f, movz = 0.f;

    for (int c0 = 0; c0 < deg; c0 += 32) {
      const int nv = min(32, deg - c0);
      const int el = lane & 31;
      const int eidv = eid[rs + c0 + min(el, nv - 1)];
      const int sv = eidx[eidv];
      float rx = cdx - coord[(size_t)sv*3 + 0];
      float ry = cdy - coord[(size_t)sv*3 + 1];
      float rz = cdz - coord[(size_t)sv*3 + 2];
      float dist = sqrtf(rx*rx + ry*ry + rz*rz);

      const int s0 = __shfl(sv, cl),        s1 = __shfl(sv, 16 + cl);
      const int ef0 = __shfl(eidv, cl),     ef1 = __shfl(eidv, 16 + cl);
      const float dist0 = __shfl(dist, cl), dist1 = __shfl(dist, 16 + cl);

      // ---- GEMM1: h = silu(m_in @ W1)  [32x192]@[192x128] ----
      f32x4 acc1[2][8];
      #pragma unroll
      for (int rt = 0; rt < 2; ++rt)
        #pragma unroll
        for (int nt = 0; nt < 8; ++nt) acc1[rt][nt] = (f32x4){0.f,0.f,0.f,0.f};
      #pragma unroll
      for (int kb = 0; kb < 6; ++kb) {
        bf16x8 af0, af1;
        if (kb < 2) {
          af0 = ldf8(node_feat + (size_t)s0*64 + kb*32 + g8);
          af1 = ldf8(node_feat + (size_t)s1*64 + kb*32 + g8);
        } else if (kb < 4) {          // dst row: identical for all 32 rows
          af0 = ldf8(node_feat + (size_t)n*64 + (kb-2)*32 + g8);
          af1 = af0;
        } else if (kb == 4) {         // rbf: centers c_i = i*10/31, i = g8+j
          #pragma unroll
          for (int j = 0; j < 8; ++j) {
            float c = (float)(g8 + j) * (10.0f / 31.0f);
            float u0 = dist0 - c, u1 = dist1 - c;
            af0[j] = (short)f2bf(__expf(-10.0f * u0 * u0));
            af1[j] = (short)f2bf(__expf(-10.0f * u1 * u1));
          }
        } else {                      // edge_feat cols 160..175 + zero pad
          if (g8 < 16) {
            af0 = ldf8(edge_feat + (size_t)ef0*16 + g8);
            af1 = ldf8(edge_feat + (size_t)ef1*16 + g8);
          } else {
            af0 = (bf16x8){0,0,0,0,0,0,0,0};
            af1 = af0;
          }
        }
        #pragma unroll
        for (int nt = 0; nt < 8; ++nt) {
          bf16x8 bw = *(const bf16x8*)(w1f + ((kb*8 + nt)*64 + lane)*8);
          acc1[0][nt] = __builtin_amdgcn_mfma_f32_16x16x32_bf16(af0, bw, acc1[0][nt], 0, 0, 0);
          acc1[1][nt] = __builtin_amdgcn_mfma_f32_16x16x32_bf16(af1, bw, acc1[1][nt], 0, 0, 0);
        }
      }
      #pragma unroll
      for (int rt = 0; rt < 2; ++rt)
        #pragma unroll
        for (int nt = 0; nt < 8; ++nt)
          #pragma unroll
          for (int r = 0; r < 4; ++r)
            myact[(rt*16 + orow4 + r)*HS2 + nt*16 + cl] = f2bf(silu_f(acc1[rt][nt][r]));
      asm volatile("" ::: "memory");  // keep h-writes before h-reads

      // ---- GEMM2: msg = silu(h @ W2)  [32x128]@[128x64] ----
      f32x4 acc2[2][4];
      #pragma unroll
      for (int rt = 0; rt < 2; ++rt)
        #pragma unroll
        for (int nt = 0; nt < 4; ++nt) acc2[rt][nt] = (f32x4){0.f,0.f,0.f,0.f};
      #pragma unroll
      for (int kb = 0; kb < 4; ++kb) {
        bf16x8 a0 = *(const bf16x8*)(myact + cl*HS2 + kb*32 + g8);
        bf16x8 a1 = *(const bf16x8*)(myact + (16 + cl)*HS2 + kb*32 + g8);
        #pragma unroll
        for (int nt = 0; nt < 4; ++nt) {
          bf16x8 bw = *(const bf16x8*)(w2f + ((kb*4 + nt)*64 + lane)*8);
          acc2[0][nt] = __builtin_amdgcn_mfma_f32_16x16x32_bf16(a0, bw, acc2[0][nt], 0, 0, 0);
          acc2[1][nt] = __builtin_amdgcn_mfma_f32_16x16x32_bf16(a1, bw, acc2[1][nt], 0, 0, 0);
        }
      }
      asm volatile("" ::: "memory");
      // m -> act cols 0..63 (aliases h cols 0..63; h reads already issued)
      // + masked register accumulation of msg column sums
      {
        float mk[2][4];
        #pragma unroll
        for (int rt = 0; rt < 2; ++rt)
          #pragma unroll
          for (int r = 0; r < 4; ++r)
            mk[rt][r] = (rt*16 + orow4 + r < nv) ? 1.0f : 0.0f;
        #pragma unroll
        for (int rt = 0; rt < 2; ++rt)
          #pragma unroll
          for (int nt = 0; nt < 4; ++nt)
            #pragma unroll
            for (int r = 0; r < 4; ++r) {
              float v = silu_f(acc2[rt][nt][r]);
              myact[(rt*16 + orow4 + r)*HS2 + nt*16 + cl] = f2bf(v);
              msg_part[nt] += v * mk[rt][r];
            }
        asm volatile("" ::: "memory");  // keep m-writes before m-reads

        // ---- GEMM3: s = silu(msg @ W3) @ w2_mov ; masked mov accumulation --
        f32x4 acc3[2][4];
        #pragma unroll
        for (int rt = 0; rt < 2; ++rt)
          #pragma unroll
          for (int nt = 0; nt < 4; ++nt) acc3[rt][nt] = (f32x4){0.f,0.f,0.f,0.f};
        #pragma unroll
        for (int kb = 0; kb < 2; ++kb) {
          bf16x8 a0 = *(const bf16x8*)(myact + cl*HS2 + kb*32 + g8);
          bf16x8 a1 = *(const bf16x8*)(myact + (16 + cl)*HS2 + kb*32 + g8);
          #pragma unroll
          for (int nt = 0; nt < 4; ++nt) {
            bf16x8 bw = *(const bf16x8*)(w3f + ((kb*4 + nt)*64 + lane)*8);
            acc3[0][nt] = __builtin_amdgcn_mfma_f32_16x16x32_bf16(a0, bw, acc3[0][nt], 0, 0, 0);
            acc3[1][nt] = __builtin_amdgcn_mfma_f32_16x16x32_bf16(a1, bw, acc3[1][nt], 0, 0, 0);
          }
        }
        float prt[2][4];
        #pragma unroll
        for (int rt = 0; rt < 2; ++rt)
          #pragma unroll
          for (int r = 0; r < 4; ++r) prt[rt][r] = 0.f;
        #pragma unroll
        for (int nt = 0; nt < 4; ++nt)
          #pragma unroll
          for (int rt = 0; rt < 2; ++rt)
            #pragma unroll
            for (int r = 0; r < 4; ++r)
              prt[rt][r] += silu_f(acc3[rt][nt][r]) * w2m_r[nt];
        #pragma unroll
        for (int off = 1; off < 16; off <<= 1)
          #pragma unroll
          for (int rt = 0; rt < 2; ++rt)
            #pragma unroll
            for (int r = 0; r < 4; ++r) prt[rt][r] += __shfl_xor(prt[rt][r], off, 64);
        // each row counted by 16 cl-lanes -> divide by 16 after final reduce
        #pragma unroll
        for (int rt = 0; rt < 2; ++rt)
          #pragma unroll
          for (int r = 0; r < 4; ++r) {
            int row = rt*16 + orow4 + r;
            float rxr = __shfl(rx, row), ryr = __shfl(ry, row), rzr = __shfl(rz, row);
            float sm  = prt[rt][r] * mk[rt][r];
            movx += rxr * sm; movy += ryr * sm; movz += rzr * sm;
          }
      }
    }

    // ---- per-node reductions + non-atomic writes ----
    #pragma unroll
    for (int nt = 0; nt < 4; ++nt) {
      msg_part[nt] += __shfl_xor(msg_part[nt], 16, 64);
      msg_part[nt] += __shfl_xor(msg_part[nt], 32, 64);
    }
    if (lane < 16) {
      #pragma unroll
      for (int nt = 0; nt < 4; ++nt)
        msg_tot[(size_t)n*64 + nt*16 + lane] = msg_part[nt];
    }
    #pragma unroll
    for (int off = 1; off < 64; off <<= 1) {
      movx += __shfl_xor(movx, off, 64);
      movy += __shfl_xor(movy, off, 64);
      movz += __shfl_xor(movz, off, 64);
    }
    if (lane == 0) {
      out_coord[(size_t)n*3 + 0] = cdx + movx * (1.0f/16.0f);
      out_coord[(size_t)n*3 + 1] = cdy + movy * (1.0f/16.0f);
      out_coord[(size_t)n*3 + 2] = cdz + movz * (1.0f/16.0f);
    }
  }
}

// ---------------------------------------------------------------------------
// Node kernel: new_feat = node_feat + silu([feat|total_msg]@W1n + b1)@W2n + b2
// ---------------------------------------------------------------------------
__global__ __launch_bounds__(256, 1) void egnn_node(
    const float* __restrict__ node_feat, const float* __restrict__ msg_tot,
    const float* __restrict__ w1n, const float* __restrict__ b1n,
    const float* __restrict__ w2n, const float* __restrict__ b2n,
    float* __restrict__ out_feat)
{
  __shared__ unsigned short w1f[4*8*64*8];   // 32KB
  __shared__ unsigned short w2f[4*4*64*8];   // 16KB
  __shared__ unsigned short a_lds[64*HS2];
  __shared__ unsigned short h_lds[64*HS2];
  __shared__ float b1s[128];
  __shared__ float b2s[64];

  const int t = threadIdx.x, lane = t & 63, wv = t >> 6;
  const int n0 = blockIdx.x * 64;
  const int row16 = wv*16 + (lane & 15);
  const int g8 = (lane >> 4) * 8;
  const int orow = wv*16 + (lane >> 4)*4;
  const int ocol = lane & 15;

  for (int i = t; i < 4*8*64*8; i += 256) {
    int j = i & 7, l = (i >> 3) & 63, nt = (i >> 9) & 7, kb = i >> 12;
    w1f[i] = f2bf(w1n[(kb*32 + (l >> 4)*8 + j)*128 + nt*16 + (l & 15)]);
  }
  for (int i = t; i < 4*4*64*8; i += 256) {
    int j = i & 7, l = (i >> 3) & 63, nt = (i >> 9) & 3, kb = i >> 11;
    w2f[i] = f2bf(w2n[(kb*32 + (l >> 4)*8 + j)*64 + nt*16 + (l & 15)]);
  }
  if (t < 128) b1s[t] = b1n[t];
  if (t < 64)  b2s[t] = b2n[t];

  {
    const int nd = t >> 2, q = t & 3;
    const int gn = n0 + nd;
    unsigned short* arow = a_lds + nd*HS2;
    if (gn < NN) {
      const float4* pf = (const float4*)(node_feat + (size_t)gn*64 + q*16);
      const float4* pm = (const float4*)(msg_tot + (size_t)gn*64 + q*16);
      #pragma unroll
      for (int qq = 0; qq < 4; ++qq) {
        float4 v = pf[qq]; int c = q*16 + qq*4;
        arow[c] = f2bf(v.x); arow[c+1] = f2bf(v.y); arow[c+2] = f2bf(v.z); arow[c+3] = f2bf(v.w);
      }
      #pragma unroll
      for (int qq = 0; qq < 4; ++qq) {
        float4 v = pm[qq]; int c = 64 + q*16 + qq*4;
        arow[c] = f2bf(v.x); arow[c+1] = f2bf(v.y); arow[c+2] = f2bf(v.z); arow[c+3] = f2bf(v.w);
      }
    } else {
      #pragma unroll
      for (int c = 0; c < 16; ++c) { arow[q*16 + c] = 0; arow[64 + q*16 + c] = 0; }
    }
  }
  __syncthreads();
  {
    f32x4 acc[8];
    #pragma unroll
    for (int nt = 0; nt < 8; ++nt) acc[nt] = (f32x4){0.f,0.f,0.f,0.f};
    #pragma unroll
    for (int kb = 0; kb < 4; ++kb) {
      bf16x8 af = *(const bf16x8*)(a_lds + row16*HS2 + kb*32 + g8);
      #pragma unroll
      for (int nt = 0; nt < 8; ++nt) {
        bf16x8 bfv = *(const bf16x8*)(w1f + ((kb*8 + nt)*64 + lane)*8);
        acc[nt] = __builtin_amdgcn_mfma_f32_16x16x32_bf16(af, bfv, acc[nt], 0, 0, 0);
      }
    }
    #pragma unroll
    for (int nt = 0; nt < 8; ++nt)
      #pragma unroll
      for (int r = 0; r < 4; ++r) {
        int col = nt*16 + ocol;
        h_lds[(orow + r)*HS2 + col] = f2bf(silu_f(acc[nt][r] + b1s[col]));
      }
  }
  __syncthreads();
  {
    f32x4 acc[4];
    #pragma unroll
    for (int nt = 0; nt < 4; ++nt) acc[nt] = (f32x4){0.f,0.f,0.f,0.f};
    #pragma unroll
    for (int kb = 0; kb < 4; ++kb) {
      bf16x8 af = *(const bf16x8*)(h_lds + row16*HS2 + kb*32 + g8);
      #pragma unroll
      for (int nt = 0; nt < 4; ++nt) {
        bf16x8 bfv = *(const bf16x8*)(w2f + ((kb*4 + nt)*64 + lane)*8);
        acc[nt] = __builtin_amdgcn_mfma_f32_16x16x32_bf16(af, bfv, acc[nt], 0, 0, 0);
      }
    }
    #pragma unroll
    for (int nt = 0; nt < 4; ++nt)
      #pragma unroll
      for (int r = 0; r < 4; ++r) {
        int row = orow + r, gn = n0 + row;
        if (gn < NN) {
          int col = nt*16 + ocol;
          out_feat[(size_t)gn*64 + col] = acc[nt][r] + b2s[col] + node_feat[(size_t)gn*64 + col];
        }
      }
  }
}

extern "C" void kernel_launch(void* const* d_in, const int* in_sizes, int n_in,
                              void* d_out, int out_size, void* d_ws, size_t ws_size,
                              hipStream_t stream) {
  (void)in_sizes; (void)n_in; (void)out_size; (void)ws_size;
  const float* node_feat = (const float*)d_in[0];
  const float* coord     = (const float*)d_in[1];
  const float* edge_feat = (const float*)d_in[2];
  const int*   eidx      = (const int*)d_in[3];
  const float* w1_msg    = (const float*)d_in[4];
  const float* w2_msg    = (const float*)d_in[5];
  const float* w1_mov    = (const float*)d_in[6];
  const float* w2_mov    = (const float*)d_in[7];
  const float* w1n       = (const float*)d_in[9];
  const float* b1n       = (const float*)d_in[10];
  const float* w2n       = (const float*)d_in[11];
  const float* b2n       = (const float*)d_in[12];

  float* out_feat  = (float*)d_out;
  float* out_coord = out_feat + (size_t)NN * 64;

  // workspace layout (~19.8 MB)
  int*   count     = (int*)d_ws;                     // 50000 (padded 50048)
  int*   row_start = count + 50048;                  // 50001
  int*   cursor    = row_start + 50048;              // 50001
  float* msg_tot   = (float*)(cursor + 50048);       // 3.2M floats
  int*   eid       = (int*)(msg_tot + (size_t)NN*64);// 1.6M ints

  hipMemsetAsync(count, 0, NN * sizeof(int), stream);
  hist_k<<<2048, 256, 0, stream>>>(eidx, count);
  scan_k<<<1, SCAN_T, 0, stream>>>(count, row_start, cursor);
  scatter_k<<<2048, 256, 0, stream>>>(eidx, cursor, eid);
  egnn_edge<<<256, 512, 0, stream>>>(node_feat, coord, edge_feat, eidx,
      row_start, eid, w1_msg, w2_msg, w1_mov, w2_mov, msg_tot, out_coord);
  egnn_node<<<(NN + 63) / 64, 256, 0, stream>>>(node_feat, msg_tot,
      w1n, b1n, w2n, b2n, out_feat);
}

// Round 5
// 632.417 us; speedup vs baseline: 1.5190x; 1.5190x over previous
//
#include <hip/hip_runtime.h>
#include <hip/hip_bf16.h>

#define E_TOT   1600000
#define NN      50000
#define K1      176     // msg MLP input dim (2*64+32+16)
#define H1      128     // MSG_HID
#define HS2     136     // act row stride (ushorts), 272B, 16B aligned
#define NGC     (E_TOT / 32)   // 50000 exact 32-edge chunks
#define NB      196            // scan blocks (196*256 >= 50001)

typedef __attribute__((ext_vector_type(8))) short bf16x8;
typedef __attribute__((ext_vector_type(4))) float f32x4;
typedef unsigned short u16;

__device__ __forceinline__ u16 f2bf(float x) {
  return __builtin_bit_cast(u16, __float2bfloat16(x));   // native RNE cvt
}
__device__ __forceinline__ float silu_f(float x) { return x / (1.0f + __expf(-x)); }

__device__ __forceinline__ bf16x8 ldf8(const float* __restrict__ p) {
  float4 a = ((const float4*)p)[0];
  float4 b = ((const float4*)p)[1];
  bf16x8 r;
  r[0] = (short)f2bf(a.x); r[1] = (short)f2bf(a.y);
  r[2] = (short)f2bf(a.z); r[3] = (short)f2bf(a.w);
  r[4] = (short)f2bf(b.x); r[5] = (short)f2bf(b.y);
  r[6] = (short)f2bf(b.z); r[7] = (short)f2bf(b.w);
  return r;
}

struct Feats { bf16x8 s0a, s0b, s1a, s1b, d0a, d0b, d1a, d1b, e0, e1; };

__device__ __forceinline__ void load_feats(Feats& f, int use16,
    const u16* __restrict__ nf16, const float* __restrict__ nf,
    const u16* __restrict__ ef16, const float* __restrict__ ef,
    int s0, int s1, int d0, int d1, int e0i, int e1i, int g8)
{
  if (use16) {
    f.s0a = *(const bf16x8*)(nf16 + (size_t)s0*64 + g8);
    f.s0b = *(const bf16x8*)(nf16 + (size_t)s0*64 + 32 + g8);
    f.s1a = *(const bf16x8*)(nf16 + (size_t)s1*64 + g8);
    f.s1b = *(const bf16x8*)(nf16 + (size_t)s1*64 + 32 + g8);
    f.d0a = *(const bf16x8*)(nf16 + (size_t)d0*64 + g8);
    f.d0b = *(const bf16x8*)(nf16 + (size_t)d0*64 + 32 + g8);
    f.d1a = *(const bf16x8*)(nf16 + (size_t)d1*64 + g8);
    f.d1b = *(const bf16x8*)(nf16 + (size_t)d1*64 + 32 + g8);
    if (g8 < 16) {
      f.e0 = *(const bf16x8*)(ef16 + (size_t)e0i*16 + g8);
      f.e1 = *(const bf16x8*)(ef16 + (size_t)e1i*16 + g8);
    } else { f.e0 = (bf16x8){0,0,0,0,0,0,0,0}; f.e1 = f.e0; }
  } else {
    f.s0a = ldf8(nf + (size_t)s0*64 + g8);
    f.s0b = ldf8(nf + (size_t)s0*64 + 32 + g8);
    f.s1a = ldf8(nf + (size_t)s1*64 + g8);
    f.s1b = ldf8(nf + (size_t)s1*64 + 32 + g8);
    f.d0a = ldf8(nf + (size_t)d0*64 + g8);
    f.d0b = ldf8(nf + (size_t)d0*64 + 32 + g8);
    f.d1a = ldf8(nf + (size_t)d1*64 + g8);
    f.d1b = ldf8(nf + (size_t)d1*64 + 32 + g8);
    if (g8 < 16) {
      f.e0 = ldf8(ef + (size_t)e0i*16 + g8);
      f.e1 = ldf8(ef + (size_t)e1i*16 + g8);
    } else { f.e0 = (bf16x8){0,0,0,0,0,0,0,0}; f.e1 = f.e0; }
  }
}

// ---------------------------------------------------------------------------
// CSR build: histogram -> 3-kernel multi-block scan -> scatter by dst.
// ---------------------------------------------------------------------------
__global__ void hist_k(const int* __restrict__ eidx, int* __restrict__ count) {
  int i = blockIdx.x * blockDim.x + threadIdx.x;
  int stride = gridDim.x * blockDim.x;
  for (; i < E_TOT; i += stride) atomicAdd(&count[eidx[E_TOT + i]], 1);
}

__global__ __launch_bounds__(256) void scanA_k(const int* __restrict__ count,
                                               int* __restrict__ bsum) {
  __shared__ int sm[256];
  int idx = blockIdx.x * 256 + threadIdx.x;
  sm[threadIdx.x] = (idx < NN) ? count[idx] : 0;
  __syncthreads();
  for (int off = 128; off > 0; off >>= 1) {
    if (threadIdx.x < off) sm[threadIdx.x] += sm[threadIdx.x + off];
    __syncthreads();
  }
  if (threadIdx.x == 0) bsum[blockIdx.x] = sm[0];
}

__global__ __launch_bounds__(256) void scanB_k(const int* __restrict__ bsum,
                                               int* __restrict__ boff) {
  __shared__ int sm[256];
  int t = threadIdx.x;
  int v = (t < NB) ? bsum[t] : 0;
  sm[t] = v; __syncthreads();
  for (int off = 1; off < 256; off <<= 1) {
    int x = (t >= off) ? sm[t - off] : 0;
    __syncthreads();
    sm[t] += x;
    __syncthreads();
  }
  boff[t] = sm[t] - v;                 // exclusive prefix of block sums
}

__global__ __launch_bounds__(256) void scanC_k(const int* __restrict__ count,
                                               const int* __restrict__ boff,
                                               int* __restrict__ cursor) {
  __shared__ int sm[256];
  int idx = blockIdx.x * 256 + threadIdx.x, t = threadIdx.x;
  int v = (idx < NN) ? count[idx] : 0;
  sm[t] = v; __syncthreads();
  for (int off = 1; off < 256; off <<= 1) {
    int x = (t >= off) ? sm[t - off] : 0;
    __syncthreads();
    sm[t] += x;
    __syncthreads();
  }
  if (idx < NN) cursor[idx] = boff[blockIdx.x] + sm[t] - v;
}

__global__ void scatter_k(const int* __restrict__ eidx, int* __restrict__ cursor,
                          int* __restrict__ eid) {
  int i = blockIdx.x * blockDim.x + threadIdx.x;
  int stride = gridDim.x * blockDim.x;
  for (; i < E_TOT; i += stride) {
    int d = eidx[E_TOT + i];
    int pos = atomicAdd(&cursor[d], 1);
    eid[pos] = i;
  }
}

// fp32 -> bf16 bulk converter (n4 = element count / 4)
__global__ void cvt_k(const float* __restrict__ src, u16* __restrict__ dst, int n4) {
  int i = blockIdx.x * blockDim.x + threadIdx.x;
  int stride = gridDim.x * blockDim.x;
  for (; i < n4; i += stride) {
    float4 v = ((const float4*)src)[i];
    union { u16 u[4]; uint2 d; } p;
    p.u[0] = f2bf(v.x); p.u[1] = f2bf(v.y); p.u[2] = f2bf(v.z); p.u[3] = f2bf(v.w);
    ((uint2*)dst)[i] = p.d;
  }
}

// ---------------------------------------------------------------------------
// Edge kernel v5: exact 32-edge chunks over the dst-sorted edge list, with
// segmented (per-node-run) reduction and boundary atomics. Software-pipelined:
// chunk t+1's index/coord/feature gathers are issued under chunk t's GEMMs.
// Fragment convention (16x16x32 bf16): A elem j of lane l = A[l%16][(l/16)*8+j],
// B elem j = B[(l/16)*8+j][l%16] (same k-map => permutation-safe).
// C/D: col = lane&15, row = (lane>>4)*4 + reg   (HW-verified).
// ---------------------------------------------------------------------------
__global__ __launch_bounds__(512, 2) void egnn_edge(
    const float* __restrict__ node_feat, const float* __restrict__ coord,
    const float* __restrict__ edge_feat, const int* __restrict__ eidx,
    const int* __restrict__ eid,
    const float* __restrict__ w1_msg, const float* __restrict__ w2_msg,
    const float* __restrict__ w1_mov, const float* __restrict__ w2_mov,
    const u16* __restrict__ nf16, const u16* __restrict__ ef16, int use16,
    float* __restrict__ msg_tot, float* __restrict__ out_coord)
{
  __shared__ u16 w1f[6*8*64*8];     // 48KB  [kb<6][nt<8][lane][8]
  __shared__ u16 w2f[4*4*64*8];     // 16KB
  __shared__ u16 w3f[2*4*64*8];     // 8KB
  __shared__ u16 act[8][32*HS2];    // 69.6KB, per-wave h (cols0..127) / m (cols0..63)

  const int t = threadIdx.x;
  const int lane = t & 63;
  const int wv = t >> 6;

  // ---- stage weight fragments (once per block) ----
  for (int i = t; i < 6*8*64*8; i += 512) {
    int j = i & 7, l = (i >> 3) & 63, nt = (i >> 9) & 7, kb = i >> 12;
    int k = kb*32 + (l >> 4)*8 + j;
    w1f[i] = f2bf(k < K1 ? w1_msg[k*H1 + nt*16 + (l & 15)] : 0.0f);
  }
  for (int i = t; i < 4*4*64*8; i += 512) {
    int j = i & 7, l = (i >> 3) & 63, nt = (i >> 9) & 3, kb = i >> 11;
    w2f[i] = f2bf(w2_msg[(kb*32 + (l >> 4)*8 + j)*64 + nt*16 + (l & 15)]);
  }
  for (int i = t; i < 2*4*64*8; i += 512) {
    int j = i & 7, l = (i >> 3) & 63, nt = (i >> 9) & 3, kb = i >> 11;
    w3f[i] = f2bf(w1_mov[(kb*32 + (l >> 4)*8 + j)*64 + nt*16 + (l & 15)]);
  }

  const int cl = lane & 15;           // A row within 16-tile / C col
  const int g8 = (lane >> 4) * 8;     // k sub-offset
  const int orow4 = (lane >> 4) * 4;  // C row base within 16-tile
  const int el = lane & 31;           // chunk row (duplicated upper half)
  float w2m_r[4];
  #pragma unroll
  for (int nt = 0; nt < 4; ++nt) w2m_r[nt] = w2_mov[nt*16 + cl];

  __syncthreads();                    // weights ready; no barriers after this

  u16* const myact = &act[wv][0];
  const int NW = gridDim.x * 8;

  int g = blockIdx.x * 8 + wv;
  if (g >= NGC) return;

  // ---- prologue: load chunk g fully ----
  int ei = eid[g*32 + el];
  int sv = eidx[ei];
  int dv = eidx[E_TOT + ei];
  float rx = coord[(size_t)dv*3+0] - coord[(size_t)sv*3+0];
  float ry = coord[(size_t)dv*3+1] - coord[(size_t)sv*3+1];
  float rz = coord[(size_t)dv*3+2] - coord[(size_t)sv*3+2];
  float dist = sqrtf(rx*rx + ry*ry + rz*rz);
  {
    int s0 = __shfl(sv, cl), s1 = __shfl(sv, 16 + cl);
    int d0 = __shfl(dv, cl), d1 = __shfl(dv, 16 + cl);
    int e0i = __shfl(ei, cl), e1i = __shfl(ei, 16 + cl);
    float dist0 = __shfl(dist, cl), dist1 = __shfl(dist, 16 + cl);
    // stash dist0/1 into rx-side scalars reused below via variables:
    // (kept in dedicated vars declared next)
    (void)s0; (void)s1; (void)d0; (void)d1; (void)e0i; (void)e1i;
    (void)dist0; (void)dist1;
  }
  float dist0 = __shfl(dist, cl), dist1 = __shfl(dist, 16 + cl);
  Feats cf;
  {
    int s0 = __shfl(sv, cl), s1 = __shfl(sv, 16 + cl);
    int d0 = __shfl(dv, cl), d1 = __shfl(dv, 16 + cl);
    int e0i = __shfl(ei, cl), e1i = __shfl(ei, 16 + cl);
    load_feats(cf, use16, nf16, node_feat, ef16, edge_feat,
               s0, s1, d0, d1, e0i, e1i, g8);
  }

  while (true) {
    const int gn = g + NW;
    const bool hn = gn < NGC;

    // ---- pipeline stage 0: issue next chunk's eid load (independent) ----
    int nei = 0;
    if (hn) nei = eid[gn*32 + el];

    // ---- rbf fragments for current chunk (VALU) ----
    bf16x8 rbf0, rbf1;
    #pragma unroll
    for (int j = 0; j < 8; ++j) {
      float c = (float)(g8 + j) * (10.0f / 31.0f);
      float u0 = dist0 - c, u1 = dist1 - c;
      rbf0[j] = (short)f2bf(__expf(-10.0f * u0 * u0));
      rbf1[j] = (short)f2bf(__expf(-10.0f * u1 * u1));
    }

    // ---- GEMM1: h = silu(m_in @ W1)  [32x192]@[192x128] ----
    f32x4 acc1[2][8];
    #pragma unroll
    for (int rt = 0; rt < 2; ++rt)
      #pragma unroll
      for (int nt = 0; nt < 8; ++nt) acc1[rt][nt] = (f32x4){0.f,0.f,0.f,0.f};
    #pragma unroll
    for (int kb = 0; kb < 6; ++kb) {
      bf16x8 af0, af1;
      if      (kb == 0) { af0 = cf.s0a; af1 = cf.s1a; }
      else if (kb == 1) { af0 = cf.s0b; af1 = cf.s1b; }
      else if (kb == 2) { af0 = cf.d0a; af1 = cf.d1a; }
      else if (kb == 3) { af0 = cf.d0b; af1 = cf.d1b; }
      else if (kb == 4) { af0 = rbf0;   af1 = rbf1;   }
      else              { af0 = cf.e0;  af1 = cf.e1;  }
      #pragma unroll
      for (int nt = 0; nt < 8; ++nt) {
        bf16x8 bw = *(const bf16x8*)(w1f + ((kb*8 + nt)*64 + lane)*8);
        acc1[0][nt] = __builtin_amdgcn_mfma_f32_16x16x32_bf16(af0, bw, acc1[0][nt], 0, 0, 0);
        acc1[1][nt] = __builtin_amdgcn_mfma_f32_16x16x32_bf16(af1, bw, acc1[1][nt], 0, 0, 0);
      }
    }
    #pragma unroll
    for (int rt = 0; rt < 2; ++rt)
      #pragma unroll
      for (int nt = 0; nt < 8; ++nt)
        #pragma unroll
        for (int r = 0; r < 4; ++r)
          myact[(rt*16 + orow4 + r)*HS2 + nt*16 + cl] = f2bf(silu_f(acc1[rt][nt][r]));

    // ---- pipeline stage 1: next chunk's dst/src ids (nei resolved by now) --
    int nsv = 0, ndv = 0;
    if (hn) { nsv = eidx[nei]; ndv = eidx[E_TOT + nei]; }

    // ---- GEMM2: msg = silu(h @ W2)  [32x128]@[128x64] ----
    f32x4 acc2[2][4];
    #pragma unroll
    for (int rt = 0; rt < 2; ++rt)
      #pragma unroll
      for (int nt = 0; nt < 4; ++nt) acc2[rt][nt] = (f32x4){0.f,0.f,0.f,0.f};
    #pragma unroll
    for (int kb = 0; kb < 4; ++kb) {
      bf16x8 a0 = *(const bf16x8*)(myact + cl*HS2 + kb*32 + g8);
      bf16x8 a1 = *(const bf16x8*)(myact + (16 + cl)*HS2 + kb*32 + g8);
      #pragma unroll
      for (int nt = 0; nt < 4; ++nt) {
        bf16x8 bw = *(const bf16x8*)(w2f + ((kb*4 + nt)*64 + lane)*8);
        acc2[0][nt] = __builtin_amdgcn_mfma_f32_16x16x32_bf16(a0, bw, acc2[0][nt], 0, 0, 0);
        acc2[1][nt] = __builtin_amdgcn_mfma_f32_16x16x32_bf16(a1, bw, acc2[1][nt], 0, 0, 0);
      }
    }
    // mval regs + m -> act cols 0..63 (aliases h; h reads already done)
    float mval[2][4][4];
    #pragma unroll
    for (int rt = 0; rt < 2; ++rt)
      #pragma unroll
      for (int nt = 0; nt < 4; ++nt)
        #pragma unroll
        for (int r = 0; r < 4; ++r) {
          float v = silu_f(acc2[rt][nt][r]);
          mval[rt][nt][r] = v;
          myact[(rt*16 + orow4 + r)*HS2 + nt*16 + cl] = f2bf(v);
        }

    // ---- pipeline stage 2: next chunk's geometry + feature gathers ----
    float nrx = 0.f, nry = 0.f, nrz = 0.f, ndist0 = 0.f, ndist1 = 0.f;
    Feats nf_;
    if (hn) {
      nrx = coord[(size_t)ndv*3+0] - coord[(size_t)nsv*3+0];
      nry = coord[(size_t)ndv*3+1] - coord[(size_t)nsv*3+1];
      nrz = coord[(size_t)ndv*3+2] - coord[(size_t)nsv*3+2];
      float nd = sqrtf(nrx*nrx + nry*nry + nrz*nrz);
      ndist0 = __shfl(nd, cl); ndist1 = __shfl(nd, 16 + cl);
      int s0 = __shfl(nsv, cl), s1 = __shfl(nsv, 16 + cl);
      int d0 = __shfl(ndv, cl), d1 = __shfl(ndv, 16 + cl);
      int e0i = __shfl(nei, cl), e1i = __shfl(nei, 16 + cl);
      load_feats(nf_, use16, nf16, node_feat, ef16, edge_feat,
                 s0, s1, d0, d1, e0i, e1i, g8);
    }

    // ---- GEMM3: s = silu(msg @ W3) @ w2_mov ----
    f32x4 acc3[2][4];
    #pragma unroll
    for (int rt = 0; rt < 2; ++rt)
      #pragma unroll
      for (int nt = 0; nt < 4; ++nt) acc3[rt][nt] = (f32x4){0.f,0.f,0.f,0.f};
    #pragma unroll
    for (int kb = 0; kb < 2; ++kb) {
      bf16x8 a0 = *(const bf16x8*)(myact + cl*HS2 + kb*32 + g8);
      bf16x8 a1 = *(const bf16x8*)(myact + (16 + cl)*HS2 + kb*32 + g8);
      #pragma unroll
      for (int nt = 0; nt < 4; ++nt) {
        bf16x8 bw = *(const bf16x8*)(w3f + ((kb*4 + nt)*64 + lane)*8);
        acc3[0][nt] = __builtin_amdgcn_mfma_f32_16x16x32_bf16(a0, bw, acc3[0][nt], 0, 0, 0);
        acc3[1][nt] = __builtin_amdgcn_mfma_f32_16x16x32_bf16(a1, bw, acc3[1][nt], 0, 0, 0);
      }
    }
    float prt[2][4];
    #pragma unroll
    for (int rt = 0; rt < 2; ++rt)
      #pragma unroll
      for (int r = 0; r < 4; ++r) prt[rt][r] = 0.f;
    #pragma unroll
    for (int nt = 0; nt < 4; ++nt)
      #pragma unroll
      for (int rt = 0; rt < 2; ++rt)
        #pragma unroll
        for (int r = 0; r < 4; ++r)
          prt[rt][r] += silu_f(acc3[rt][nt][r]) * w2m_r[nt];
    #pragma unroll
    for (int off = 1; off < 16; off <<= 1)
      #pragma unroll
      for (int rt = 0; rt < 2; ++rt)
        #pragma unroll
        for (int r = 0; r < 4; ++r) prt[rt][r] += __shfl_xor(prt[rt][r], off, 64);
    // prt[rt][r] now = full row-dot for row rt*16+orow4+r, uniform in 16-group

    // per-row rel vectors (broadcast once)
    float rxv[2][4], ryv[2][4], rzv[2][4];
    #pragma unroll
    for (int rt = 0; rt < 2; ++rt)
      #pragma unroll
      for (int r = 0; r < 4; ++r) {
        int row = rt*16 + orow4 + r;
        rxv[rt][r] = __shfl(rx, row);
        ryv[rt][r] = __shfl(ry, row);
        rzv[rt][r] = __shfl(rz, row);
      }

    // ---- segmented aggregation over dst-runs (rows sorted by dst) ----
    int start = 0;
    while (start < 32) {
      int node = __shfl(dv, start);
      unsigned long long b = __ballot(dv == node);
      unsigned m32 = (unsigned)b;
      unsigned rest = ~m32 & (0xFFFFFFFFu << start);
      int end = rest ? (__ffs(rest) - 1) : 32;

      float msum[4] = {0.f, 0.f, 0.f, 0.f};
      float sx = 0.f, sy = 0.f, sz = 0.f;
      #pragma unroll
      for (int rt = 0; rt < 2; ++rt)
        #pragma unroll
        for (int r = 0; r < 4; ++r) {
          int row = rt*16 + orow4 + r;
          float mk = (row >= start && row < end) ? 1.0f : 0.0f;
          #pragma unroll
          for (int nt = 0; nt < 4; ++nt) msum[nt] += mval[rt][nt][r] * mk;
          float s = prt[rt][r] * mk;
          sx += rxv[rt][r] * s; sy += ryv[rt][r] * s; sz += rzv[rt][r] * s;
        }
      #pragma unroll
      for (int nt = 0; nt < 4; ++nt) {
        msum[nt] += __shfl_xor(msum[nt], 16, 64);
        msum[nt] += __shfl_xor(msum[nt], 32, 64);
      }
      sx += __shfl_xor(sx, 16, 64); sx += __shfl_xor(sx, 32, 64);
      sy += __shfl_xor(sy, 16, 64); sy += __shfl_xor(sy, 32, 64);
      sz += __shfl_xor(sz, 16, 64); sz += __shfl_xor(sz, 32, 64);
      if (lane < 16) {
        #pragma unroll
        for (int nt = 0; nt < 4; ++nt)
          atomicAdd(&msg_tot[(size_t)node*64 + nt*16 + lane], msum[nt]);
      }
      if (lane == 0) {
        atomicAdd(&out_coord[(size_t)node*3 + 0], sx);
        atomicAdd(&out_coord[(size_t)node*3 + 1], sy);
        atomicAdd(&out_coord[(size_t)node*3 + 2], sz);
      }
      start = end;
    }

    if (!hn) break;
    // ---- rotate pipeline ----
    g = gn;
    dv = ndv;
    rx = nrx; ry = nry; rz = nrz;
    dist0 = ndist0; dist1 = ndist1;
    cf = nf_;
  }
}

// ---------------------------------------------------------------------------
// Node kernel: new_feat = node_feat + silu([feat|total_msg]@W1n + b1)@W2n + b2
// ---------------------------------------------------------------------------
__global__ __launch_bounds__(256, 1) void egnn_node(
    const float* __restrict__ node_feat, const float* __restrict__ msg_tot,
    const float* __restrict__ w1n, const float* __restrict__ b1n,
    const float* __restrict__ w2n, const float* __restrict__ b2n,
    float* __restrict__ out_feat)
{
  __shared__ u16 w1f[4*8*64*8];   // 32KB
  __shared__ u16 w2f[4*4*64*8];   // 16KB
  __shared__ u16 a_lds[64*HS2];
  __shared__ u16 h_lds[64*HS2];
  __shared__ float b1s[128];
  __shared__ float b2s[64];

  const int t = threadIdx.x, lane = t & 63, wv = t >> 6;
  const int n0 = blockIdx.x * 64;
  const int row16 = wv*16 + (lane & 15);
  const int g8 = (lane >> 4) * 8;
  const int orow = wv*16 + (lane >> 4)*4;
  const int ocol = lane & 15;

  for (int i = t; i < 4*8*64*8; i += 256) {
    int j = i & 7, l = (i >> 3) & 63, nt = (i >> 9) & 7, kb = i >> 12;
    w1f[i] = f2bf(w1n[(kb*32 + (l >> 4)*8 + j)*128 + nt*16 + (l & 15)]);
  }
  for (int i = t; i < 4*4*64*8; i += 256) {
    int j = i & 7, l = (i >> 3) & 63, nt = (i >> 9) & 3, kb = i >> 11;
    w2f[i] = f2bf(w2n[(kb*32 + (l >> 4)*8 + j)*64 + nt*16 + (l & 15)]);
  }
  if (t < 128) b1s[t] = b1n[t];
  if (t < 64)  b2s[t] = b2n[t];

  {
    const int nd = t >> 2, q = t & 3;
    const int gn = n0 + nd;
    u16* arow = a_lds + nd*HS2;
    if (gn < NN) {
      const float4* pf = (const float4*)(node_feat + (size_t)gn*64 + q*16);
      const float4* pm = (const float4*)(msg_tot + (size_t)gn*64 + q*16);
      #pragma unroll
      for (int qq = 0; qq < 4; ++qq) {
        float4 v = pf[qq]; int c = q*16 + qq*4;
        arow[c] = f2bf(v.x); arow[c+1] = f2bf(v.y); arow[c+2] = f2bf(v.z); arow[c+3] = f2bf(v.w);
      }
      #pragma unroll
      for (int qq = 0; qq < 4; ++qq) {
        float4 v = pm[qq]; int c = 64 + q*16 + qq*4;
        arow[c] = f2bf(v.x); arow[c+1] = f2bf(v.y); arow[c+2] = f2bf(v.z); arow[c+3] = f2bf(v.w);
      }
    } else {
      #pragma unroll
      for (int c = 0; c < 16; ++c) { arow[q*16 + c] = 0; arow[64 + q*16 + c] = 0; }
    }
  }
  __syncthreads();
  {
    f32x4 acc[8];
    #pragma unroll
    for (int nt = 0; nt < 8; ++nt) acc[nt] = (f32x4){0.f,0.f,0.f,0.f};
    #pragma unroll
    for (int kb = 0; kb < 4; ++kb) {
      bf16x8 af = *(const bf16x8*)(a_lds + row16*HS2 + kb*32 + g8);
      #pragma unroll
      for (int nt = 0; nt < 8; ++nt) {
        bf16x8 bfv = *(const bf16x8*)(w1f + ((kb*8 + nt)*64 + lane)*8);
        acc[nt] = __builtin_amdgcn_mfma_f32_16x16x32_bf16(af, bfv, acc[nt], 0, 0, 0);
      }
    }
    #pragma unroll
    for (int nt = 0; nt < 8; ++nt)
      #pragma unroll
      for (int r = 0; r < 4; ++r) {
        int col = nt*16 + ocol;
        h_lds[(orow + r)*HS2 + col] = f2bf(silu_f(acc[nt][r] + b1s[col]));
      }
  }
  __syncthreads();
  {
    f32x4 acc[4];
    #pragma unroll
    for (int nt = 0; nt < 4; ++nt) acc[nt] = (f32x4){0.f,0.f,0.f,0.f};
    #pragma unroll
    for (int kb = 0; kb < 4; ++kb) {
      bf16x8 af = *(const bf16x8*)(h_lds + row16*HS2 + kb*32 + g8);
      #pragma unroll
      for (int nt = 0; nt < 4; ++nt) {
        bf16x8 bfv = *(const bf16x8*)(w2f + ((kb*4 + nt)*64 + lane)*8);
        acc[nt] = __builtin_amdgcn_mfma_f32_16x16x32_bf16(af, bfv, acc[nt], 0, 0, 0);
      }
    }
    #pragma unroll
    for (int nt = 0; nt < 4; ++nt)
      #pragma unroll
      for (int r = 0; r < 4; ++r) {
        int row = orow + r, gn = n0 + row;
        if (gn < NN) {
          int col = nt*16 + ocol;
          out_feat[(size_t)gn*64 + col] = acc[nt][r] + b2s[col] + node_feat[(size_t)gn*64 + col];
        }
      }
  }
}

extern "C" void kernel_launch(void* const* d_in, const int* in_sizes, int n_in,
                              void* d_out, int out_size, void* d_ws, size_t ws_size,
                              hipStream_t stream) {
  (void)in_sizes; (void)n_in; (void)out_size;
  const float* node_feat = (const float*)d_in[0];
  const float* coord     = (const float*)d_in[1];
  const float* edge_feat = (const float*)d_in[2];
  const int*   eidx      = (const int*)d_in[3];
  const float* w1_msg    = (const float*)d_in[4];
  const float* w2_msg    = (const float*)d_in[5];
  const float* w1_mov    = (const float*)d_in[6];
  const float* w2_mov    = (const float*)d_in[7];
  const float* w1n       = (const float*)d_in[9];
  const float* b1n       = (const float*)d_in[10];
  const float* w2n       = (const float*)d_in[11];
  const float* b2n       = (const float*)d_in[12];

  float* out_feat  = (float*)d_out;
  float* out_coord = out_feat + (size_t)NN * 64;

  // workspace layout
  int*   count   = (int*)d_ws;                          // 50048
  int*   cursor  = count + 50048;                       // 50048
  int*   bsum    = cursor + 50048;                      // 1024
  int*   boff    = bsum + 1024;                         // 1024
  float* msg_tot = (float*)(boff + 1024);               // 3.2M floats
  int*   eid     = (int*)(msg_tot + (size_t)NN*64);     // 1.6M ints
  u16*   nf16    = (u16*)(eid + E_TOT);                 // 3.2M u16 (6.4 MB)
  u16*   ef16    = nf16 + (size_t)NN*64;                // 25.6M u16 (51.2 MB)
  const size_t need16 = (size_t)((char*)(ef16 + (size_t)E_TOT*16) - (char*)d_ws);
  const int use16 = ws_size >= need16 ? 1 : 0;

  hipMemsetAsync(count, 0, NN * sizeof(int), stream);
  hipMemsetAsync(msg_tot, 0, (size_t)NN * 64 * sizeof(float), stream);
  hipMemcpyAsync(out_coord, coord, (size_t)NN * 3 * sizeof(float),
                 hipMemcpyDeviceToDevice, stream);
  if (use16) {
    cvt_k<<<2048, 256, 0, stream>>>(node_feat, nf16, NN*64/4);
    cvt_k<<<2048, 256, 0, stream>>>(edge_feat, ef16, E_TOT*16/4);
  }
  hist_k<<<2048, 256, 0, stream>>>(eidx, count);
  scanA_k<<<NB, 256, 0, stream>>>(count, bsum);
  scanB_k<<<1, 256, 0, stream>>>(bsum, boff);
  scanC_k<<<NB, 256, 0, stream>>>(count, boff, cursor);
  scatter_k<<<2048, 256, 0, stream>>>(eidx, cursor, eid);
  egnn_edge<<<256, 512, 0, stream>>>(node_feat, coord, edge_feat, eidx, eid,
      w1_msg, w2_msg, w1_mov, w2_mov, nf16, ef16, use16, msg_tot, out_coord);
  egnn_node<<<(NN + 63) / 64, 256, 0, stream>>>(node_feat, msg_tot,
      w1n, b1n, w2n, b2n, out_feat);
}

// Round 6
// 630.031 us; speedup vs baseline: 1.5248x; 1.0038x over previous
//
#include <hip/hip_runtime.h>
#include <hip/hip_bf16.h>

#define E_TOT   1600000
#define NN      50000
#define K1      176     // msg MLP input dim (2*64+32+16)
#define H1      128     // MSG_HID
#define HS2     136     // act row stride (ushorts), 272B, 16B aligned
#define NGC     (E_TOT / 32)   // 50000 exact 32-edge chunks
#define NB      196            // scan blocks (196*256 >= 50001)
#define NT_NODE ((NN + 63) / 64)

typedef __attribute__((ext_vector_type(8))) short bf16x8;
typedef __attribute__((ext_vector_type(4))) float f32x4;
typedef unsigned short u16;
typedef unsigned int u32;

__device__ __forceinline__ u16 f2bf(float x) {
  return __builtin_bit_cast(u16, __float2bfloat16(x));   // native RNE cvt
}
__device__ __forceinline__ u32 pk2bf(float lo, float hi) {
  return (u32)f2bf(lo) | ((u32)f2bf(hi) << 16);
}
__device__ __forceinline__ float silu_f(float x) { return x / (1.0f + __expf(-x)); }

__device__ __forceinline__ bf16x8 ldf8(const float* __restrict__ p) {
  float4 a = ((const float4*)p)[0];
  float4 b = ((const float4*)p)[1];
  bf16x8 r;
  r[0] = (short)f2bf(a.x); r[1] = (short)f2bf(a.y);
  r[2] = (short)f2bf(a.z); r[3] = (short)f2bf(a.w);
  r[4] = (short)f2bf(b.x); r[5] = (short)f2bf(b.y);
  r[6] = (short)f2bf(b.z); r[7] = (short)f2bf(b.w);
  return r;
}

struct Feats { bf16x8 s0a, s0b, s1a, s1b, d0a, d0b, d1a, d1b, e0, e1; };

__device__ __forceinline__ void load_feats(Feats& f, int use16,
    const u16* __restrict__ nf16, const float* __restrict__ nf,
    const float* __restrict__ ef,
    int s0, int s1, int d0, int d1, int e0i, int e1i, int g8)
{
  if (use16) {
    f.s0a = *(const bf16x8*)(nf16 + (size_t)s0*64 + g8);
    f.s0b = *(const bf16x8*)(nf16 + (size_t)s0*64 + 32 + g8);
    f.s1a = *(const bf16x8*)(nf16 + (size_t)s1*64 + g8);
    f.s1b = *(const bf16x8*)(nf16 + (size_t)s1*64 + 32 + g8);
    f.d0a = *(const bf16x8*)(nf16 + (size_t)d0*64 + g8);
    f.d0b = *(const bf16x8*)(nf16 + (size_t)d0*64 + 32 + g8);
    f.d1a = *(const bf16x8*)(nf16 + (size_t)d1*64 + g8);
    f.d1b = *(const bf16x8*)(nf16 + (size_t)d1*64 + 32 + g8);
  } else {
    f.s0a = ldf8(nf + (size_t)s0*64 + g8);
    f.s0b = ldf8(nf + (size_t)s0*64 + 32 + g8);
    f.s1a = ldf8(nf + (size_t)s1*64 + g8);
    f.s1b = ldf8(nf + (size_t)s1*64 + 32 + g8);
    f.d0a = ldf8(nf + (size_t)d0*64 + g8);
    f.d0b = ldf8(nf + (size_t)d0*64 + 32 + g8);
    f.d1a = ldf8(nf + (size_t)d1*64 + g8);
    f.d1b = ldf8(nf + (size_t)d1*64 + 32 + g8);
  }
  if (g8 < 16) {                      // edge_feat always fp32 (read-once data)
    f.e0 = ldf8(ef + (size_t)e0i*16 + g8);
    f.e1 = ldf8(ef + (size_t)e1i*16 + g8);
  } else { f.e0 = (bf16x8){0,0,0,0,0,0,0,0}; f.e1 = f.e0; }
}

// ---------------------------------------------------------------------------
// CSR build: histogram -> 3-kernel multi-block scan -> scatter by dst.
// ---------------------------------------------------------------------------
__global__ void hist_k(const int* __restrict__ eidx, int* __restrict__ count) {
  int i = blockIdx.x * blockDim.x + threadIdx.x;
  int stride = gridDim.x * blockDim.x;
  for (; i < E_TOT; i += stride) atomicAdd(&count[eidx[E_TOT + i]], 1);
}

__global__ __launch_bounds__(256) void scanA_k(const int* __restrict__ count,
                                               int* __restrict__ bsum) {
  __shared__ int sm[256];
  int idx = blockIdx.x * 256 + threadIdx.x;
  sm[threadIdx.x] = (idx < NN) ? count[idx] : 0;
  __syncthreads();
  for (int off = 128; off > 0; off >>= 1) {
    if (threadIdx.x < off) sm[threadIdx.x] += sm[threadIdx.x + off];
    __syncthreads();
  }
  if (threadIdx.x == 0) bsum[blockIdx.x] = sm[0];
}

__global__ __launch_bounds__(256) void scanB_k(const int* __restrict__ bsum,
                                               int* __restrict__ boff) {
  __shared__ int sm[256];
  int t = threadIdx.x;
  int v = (t < NB) ? bsum[t] : 0;
  sm[t] = v; __syncthreads();
  for (int off = 1; off < 256; off <<= 1) {
    int x = (t >= off) ? sm[t - off] : 0;
    __syncthreads();
    sm[t] += x;
    __syncthreads();
  }
  boff[t] = sm[t] - v;                 // exclusive prefix of block sums
}

__global__ __launch_bounds__(256) void scanC_k(const int* __restrict__ count,
                                               const int* __restrict__ boff,
                                               int* __restrict__ cursor) {
  __shared__ int sm[256];
  int idx = blockIdx.x * 256 + threadIdx.x, t = threadIdx.x;
  int v = (idx < NN) ? count[idx] : 0;
  sm[t] = v; __syncthreads();
  for (int off = 1; off < 256; off <<= 1) {
    int x = (t >= off) ? sm[t - off] : 0;
    __syncthreads();
    sm[t] += x;
    __syncthreads();
  }
  if (idx < NN) cursor[idx] = boff[blockIdx.x] + sm[t] - v;
}

__global__ void scatter_k(const int* __restrict__ eidx, int* __restrict__ cursor,
                          int* __restrict__ eid) {
  int i = blockIdx.x * blockDim.x + threadIdx.x;
  int stride = gridDim.x * blockDim.x;
  for (; i < E_TOT; i += stride) {
    int d = eidx[E_TOT + i];
    int pos = atomicAdd(&cursor[d], 1);
    eid[pos] = i;
  }
}

// fp32 -> bf16 bulk converter (n4 = element count / 4)
__global__ void cvt_k(const float* __restrict__ src, u16* __restrict__ dst, int n4) {
  int i = blockIdx.x * blockDim.x + threadIdx.x;
  int stride = gridDim.x * blockDim.x;
  for (; i < n4; i += stride) {
    float4 v = ((const float4*)src)[i];
    union { u16 u[4]; uint2 d; } p;
    p.u[0] = f2bf(v.x); p.u[1] = f2bf(v.y); p.u[2] = f2bf(v.z); p.u[3] = f2bf(v.w);
    ((uint2*)dst)[i] = p.d;
  }
}

// ---------------------------------------------------------------------------
// Edge kernel v6: v5 structure + (a) N-PERMUTED B fragments so each lane's
// MFMA outputs are ADJACENT columns of one row -> packed b128/b64 LDS writes,
// (b) W2/W3 fragments held in registers (no LDS reads for them).
// B n-maps: GEMM1 n = 8*(lane&15)+nt ; GEMM2/3 n = 4*(lane&15)+nt.
// A/B k-map (shared): k = 32*kb + (lane>>4)*8 + j  (permutation-safe).
// C/D: hw-col = lane&15, row = (lane>>4)*4 + reg   (HW-verified).
// ---------------------------------------------------------------------------
__global__ __launch_bounds__(512, 2) void egnn_edge(
    const float* __restrict__ node_feat, const float* __restrict__ coord,
    const float* __restrict__ edge_feat, const int* __restrict__ eidx,
    const int* __restrict__ eid,
    const float* __restrict__ w1_msg, const float* __restrict__ w2_msg,
    const float* __restrict__ w1_mov, const float* __restrict__ w2_mov,
    const u16* __restrict__ nf16, int use16,
    float* __restrict__ msg_tot, float* __restrict__ out_coord)
{
  __shared__ u16 w1f[6*8*64*8];     // 48KB  [kb<6][nt<8][lane][8]
  __shared__ u16 act[8][32*HS2];    // 69.6KB, per-wave h (cols0..127) / m (cols0..63)

  const int t = threadIdx.x;
  const int lane = t & 63;
  const int wv = t >> 6;
  const int cl = lane & 15;           // A row within 16-tile / C hw-col
  const int g8 = (lane >> 4) * 8;     // k sub-offset
  const int orow4 = (lane >> 4) * 4;  // C row base within 16-tile
  const int el = lane & 31;           // chunk row (duplicated upper half)

  // ---- stage W1 fragments to LDS (permuted n-map: n = 8*(l&15)+nt) ----
  for (int i = t; i < 6*8*64*8; i += 512) {
    int j = i & 7, l = (i >> 3) & 63, nt = (i >> 9) & 7, kb = i >> 12;
    int k = kb*32 + (l >> 4)*8 + j;
    int n = 8*(l & 15) + nt;
    w1f[i] = f2bf(k < K1 ? w1_msg[k*H1 + n] : 0.0f);
  }
  // ---- W2 / W3 fragments in registers (n = 4*cl+nt) ----
  bf16x8 w2r[4][4], w3r[2][4];
  #pragma unroll
  for (int kb = 0; kb < 4; ++kb)
    #pragma unroll
    for (int nt = 0; nt < 4; ++nt)
      #pragma unroll
      for (int j = 0; j < 8; ++j)
        w2r[kb][nt][j] = (short)f2bf(w2_msg[(kb*32 + g8 + j)*64 + 4*cl + nt]);
  #pragma unroll
  for (int kb = 0; kb < 2; ++kb)
    #pragma unroll
    for (int nt = 0; nt < 4; ++nt)
      #pragma unroll
      for (int j = 0; j < 8; ++j)
        w3r[kb][nt][j] = (short)f2bf(w1_mov[(kb*32 + g8 + j)*64 + 4*cl + nt]);
  float w2m_r[4];
  #pragma unroll
  for (int nt = 0; nt < 4; ++nt) w2m_r[nt] = w2_mov[4*cl + nt];

  __syncthreads();                    // weights ready; no barriers after this

  u16* const myact = &act[wv][0];
  const int NW = gridDim.x * 8;

  int g = blockIdx.x * 8 + wv;
  if (g >= NGC) return;

  // ---- prologue: load chunk g fully ----
  int ei = eid[g*32 + el];
  int sv = eidx[ei];
  int dv = eidx[E_TOT + ei];
  float rx = coord[(size_t)dv*3+0] - coord[(size_t)sv*3+0];
  float ry = coord[(size_t)dv*3+1] - coord[(size_t)sv*3+1];
  float rz = coord[(size_t)dv*3+2] - coord[(size_t)sv*3+2];
  float dist = sqrtf(rx*rx + ry*ry + rz*rz);
  float dist0 = __shfl(dist, cl), dist1 = __shfl(dist, 16 + cl);
  Feats cf;
  {
    int s0 = __shfl(sv, cl), s1 = __shfl(sv, 16 + cl);
    int d0 = __shfl(dv, cl), d1 = __shfl(dv, 16 + cl);
    int e0i = __shfl(ei, cl), e1i = __shfl(ei, 16 + cl);
    load_feats(cf, use16, nf16, node_feat, edge_feat,
               s0, s1, d0, d1, e0i, e1i, g8);
  }

  while (true) {
    const int gn = g + NW;
    const bool hn = gn < NGC;

    // ---- pipeline stage 0: next chunk's eid ----
    int nei = 0;
    if (hn) nei = eid[gn*32 + el];

    // ---- rbf fragments (current chunk) ----
    bf16x8 rbf0, rbf1;
    #pragma unroll
    for (int j = 0; j < 8; ++j) {
      float c = (float)(g8 + j) * (10.0f / 31.0f);
      float u0 = dist0 - c, u1 = dist1 - c;
      rbf0[j] = (short)f2bf(__expf(-10.0f * u0 * u0));
      rbf1[j] = (short)f2bf(__expf(-10.0f * u1 * u1));
    }

    // ---- GEMM1: h = silu(m_in @ W1)  [32x192]@[192x128] ----
    f32x4 acc1[2][8];
    #pragma unroll
    for (int rt = 0; rt < 2; ++rt)
      #pragma unroll
      for (int nt = 0; nt < 8; ++nt) acc1[rt][nt] = (f32x4){0.f,0.f,0.f,0.f};
    #pragma unroll
    for (int kb = 0; kb < 6; ++kb) {
      bf16x8 af0, af1;
      if      (kb == 0) { af0 = cf.s0a; af1 = cf.s1a; }
      else if (kb == 1) { af0 = cf.s0b; af1 = cf.s1b; }
      else if (kb == 2) { af0 = cf.d0a; af1 = cf.d1a; }
      else if (kb == 3) { af0 = cf.d0b; af1 = cf.d1b; }
      else if (kb == 4) { af0 = rbf0;   af1 = rbf1;   }
      else              { af0 = cf.e0;  af1 = cf.e1;  }
      #pragma unroll
      for (int nt = 0; nt < 8; ++nt) {
        bf16x8 bw = *(const bf16x8*)(w1f + ((kb*8 + nt)*64 + lane)*8);
        acc1[0][nt] = __builtin_amdgcn_mfma_f32_16x16x32_bf16(af0, bw, acc1[0][nt], 0, 0, 0);
        acc1[1][nt] = __builtin_amdgcn_mfma_f32_16x16x32_bf16(af1, bw, acc1[1][nt], 0, 0, 0);
      }
    }
    // packed epilogue: lane holds h[row][8*cl .. 8*cl+7] for 8 rows
    #pragma unroll
    for (int rt = 0; rt < 2; ++rt)
      #pragma unroll
      for (int r = 0; r < 4; ++r) {
        uint4 q;
        q.x = pk2bf(silu_f(acc1[rt][0][r]), silu_f(acc1[rt][1][r]));
        q.y = pk2bf(silu_f(acc1[rt][2][r]), silu_f(acc1[rt][3][r]));
        q.z = pk2bf(silu_f(acc1[rt][4][r]), silu_f(acc1[rt][5][r]));
        q.w = pk2bf(silu_f(acc1[rt][6][r]), silu_f(acc1[rt][7][r]));
        *(uint4*)(myact + (rt*16 + orow4 + r)*HS2 + 8*cl) = q;
      }
    asm volatile("" ::: "memory");    // h-writes before h-reads (program order)

    // ---- pipeline stage 1: next chunk's src/dst ids ----
    int nsv = 0, ndv = 0;
    if (hn) { nsv = eidx[nei]; ndv = eidx[E_TOT + nei]; }

    // ---- GEMM2: msg = silu(h @ W2)  [32x128]@[128x64] ----
    f32x4 acc2[2][4];
    #pragma unroll
    for (int rt = 0; rt < 2; ++rt)
      #pragma unroll
      for (int nt = 0; nt < 4; ++nt) acc2[rt][nt] = (f32x4){0.f,0.f,0.f,0.f};
    #pragma unroll
    for (int kb = 0; kb < 4; ++kb) {
      bf16x8 a0 = *(const bf16x8*)(myact + cl*HS2 + kb*32 + g8);
      bf16x8 a1 = *(const bf16x8*)(myact + (16 + cl)*HS2 + kb*32 + g8);
      #pragma unroll
      for (int nt = 0; nt < 4; ++nt) {
        acc2[0][nt] = __builtin_amdgcn_mfma_f32_16x16x32_bf16(a0, w2r[kb][nt], acc2[0][nt], 0, 0, 0);
        acc2[1][nt] = __builtin_amdgcn_mfma_f32_16x16x32_bf16(a1, w2r[kb][nt], acc2[1][nt], 0, 0, 0);
      }
    }
    asm volatile("" ::: "memory");
    // mval regs (col = 4*cl+nt) + packed m -> act cols 0..63
    float mval[2][4][4];
    #pragma unroll
    for (int rt = 0; rt < 2; ++rt)
      #pragma unroll
      for (int r = 0; r < 4; ++r) {
        #pragma unroll
        for (int nt = 0; nt < 4; ++nt) mval[rt][nt][r] = silu_f(acc2[rt][nt][r]);
        uint2 q;
        q.x = pk2bf(mval[rt][0][r], mval[rt][1][r]);
        q.y = pk2bf(mval[rt][2][r], mval[rt][3][r]);
        *(uint2*)(myact + (rt*16 + orow4 + r)*HS2 + 4*cl) = q;
      }
    asm volatile("" ::: "memory");    // m-writes before m-reads

    // ---- pipeline stage 2: next chunk's geometry + feature gathers ----
    float nrx = 0.f, nry = 0.f, nrz = 0.f, ndist0 = 0.f, ndist1 = 0.f;
    Feats nf_;
    if (hn) {
      nrx = coord[(size_t)ndv*3+0] - coord[(size_t)nsv*3+0];
      nry = coord[(size_t)ndv*3+1] - coord[(size_t)nsv*3+1];
      nrz = coord[(size_t)ndv*3+2] - coord[(size_t)nsv*3+2];
      float nd = sqrtf(nrx*nrx + nry*nry + nrz*nrz);
      ndist0 = __shfl(nd, cl); ndist1 = __shfl(nd, 16 + cl);
      int s0 = __shfl(nsv, cl), s1 = __shfl(nsv, 16 + cl);
      int d0 = __shfl(ndv, cl), d1 = __shfl(ndv, 16 + cl);
      int e0i = __shfl(nei, cl), e1i = __shfl(nei, 16 + cl);
      load_feats(nf_, use16, nf16, node_feat, edge_feat,
                 s0, s1, d0, d1, e0i, e1i, g8);
    }

    // ---- GEMM3: s = silu(msg @ W3) @ w2_mov ----
    f32x4 acc3[2][4];
    #pragma unroll
    for (int rt = 0; rt < 2; ++rt)
      #pragma unroll
      for (int nt = 0; nt < 4; ++nt) acc3[rt][nt] = (f32x4){0.f,0.f,0.f,0.f};
    #pragma unroll
    for (int kb = 0; kb < 2; ++kb) {
      bf16x8 a0 = *(const bf16x8*)(myact + cl*HS2 + kb*32 + g8);
      bf16x8 a1 = *(const bf16x8*)(myact + (16 + cl)*HS2 + kb*32 + g8);
      #pragma unroll
      for (int nt = 0; nt < 4; ++nt) {
        acc3[0][nt] = __builtin_amdgcn_mfma_f32_16x16x32_bf16(a0, w3r[kb][nt], acc3[0][nt], 0, 0, 0);
        acc3[1][nt] = __builtin_amdgcn_mfma_f32_16x16x32_bf16(a1, w3r[kb][nt], acc3[1][nt], 0, 0, 0);
      }
    }
    float prt[2][4];
    #pragma unroll
    for (int rt = 0; rt < 2; ++rt)
      #pragma unroll
      for (int r = 0; r < 4; ++r) prt[rt][r] = 0.f;
    #pragma unroll
    for (int nt = 0; nt < 4; ++nt)
      #pragma unroll
      for (int rt = 0; rt < 2; ++rt)
        #pragma unroll
        for (int r = 0; r < 4; ++r)
          prt[rt][r] += silu_f(acc3[rt][nt][r]) * w2m_r[nt];
    #pragma unroll
    for (int off = 1; off < 16; off <<= 1)
      #pragma unroll
      for (int rt = 0; rt < 2; ++rt)
        #pragma unroll
        for (int r = 0; r < 4; ++r) prt[rt][r] += __shfl_xor(prt[rt][r], off, 64);
    // prt[rt][r] = full row-dot for row rt*16+orow4+r, uniform in 16-group

    // per-row rel vectors (broadcast once)
    float rxv[2][4], ryv[2][4], rzv[2][4];
    #pragma unroll
    for (int rt = 0; rt < 2; ++rt)
      #pragma unroll
      for (int r = 0; r < 4; ++r) {
        int row = rt*16 + orow4 + r;
        rxv[rt][r] = __shfl(rx, row);
        ryv[rt][r] = __shfl(ry, row);
        rzv[rt][r] = __shfl(rz, row);
      }

    // ---- segmented aggregation over dst-runs (rows sorted by dst) ----
    int start = 0;
    while (start < 32) {
      int node = __shfl(dv, start);
      unsigned long long b = __ballot(dv == node);
      unsigned m32 = (unsigned)b;
      unsigned rest = ~m32 & (0xFFFFFFFFu << start);
      int end = rest ? (__ffs(rest) - 1) : 32;

      float msum[4] = {0.f, 0.f, 0.f, 0.f};
      float sx = 0.f, sy = 0.f, sz = 0.f;
      #pragma unroll
      for (int rt = 0; rt < 2; ++rt)
        #pragma unroll
        for (int r = 0; r < 4; ++r) {
          int row = rt*16 + orow4 + r;
          float mk = (row >= start && row < end) ? 1.0f : 0.0f;
          #pragma unroll
          for (int nt = 0; nt < 4; ++nt) msum[nt] += mval[rt][nt][r] * mk;
          float s = prt[rt][r] * mk;
          sx += rxv[rt][r] * s; sy += ryv[rt][r] * s; sz += rzv[rt][r] * s;
        }
      #pragma unroll
      for (int nt = 0; nt < 4; ++nt) {
        msum[nt] += __shfl_xor(msum[nt], 16, 64);
        msum[nt] += __shfl_xor(msum[nt], 32, 64);
      }
      sx += __shfl_xor(sx, 16, 64); sx += __shfl_xor(sx, 32, 64);
      sy += __shfl_xor(sy, 16, 64); sy += __shfl_xor(sy, 32, 64);
      sz += __shfl_xor(sz, 16, 64); sz += __shfl_xor(sz, 32, 64);
      if (lane < 16) {
        #pragma unroll
        for (int nt = 0; nt < 4; ++nt)
          atomicAdd(&msg_tot[(size_t)node*64 + 4*lane + nt], msum[nt]);
      }
      if (lane == 0) {
        atomicAdd(&out_coord[(size_t)node*3 + 0], sx);
        atomicAdd(&out_coord[(size_t)node*3 + 1], sy);
        atomicAdd(&out_coord[(size_t)node*3 + 2], sz);
      }
      start = end;
    }

    if (!hn) break;
    // ---- rotate pipeline ----
    g = gn;
    dv = ndv;
    rx = nrx; ry = nry; rz = nrz;
    dist0 = ndist0; dist1 = ndist1;
    cf = nf_;
  }
}

// ---------------------------------------------------------------------------
// Node kernel (persistent): new_feat = node_feat + silu([f|msg]@W1n+b1)@W2n+b2
// Permuted n-maps as in edge kernel; float4 output stores.
// ---------------------------------------------------------------------------
__global__ __launch_bounds__(256, 1) void egnn_node(
    const float* __restrict__ node_feat, const float* __restrict__ msg_tot,
    const float* __restrict__ w1n, const float* __restrict__ b1n,
    const float* __restrict__ w2n, const float* __restrict__ b2n,
    float* __restrict__ out_feat)
{
  __shared__ u16 w1f[4*8*64*8];   // 32KB  (n = 8*(l&15)+nt)
  __shared__ u16 w2f[4*4*64*8];   // 16KB  (n = 4*(l&15)+nt)
  __shared__ u16 a_lds[64*HS2];
  __shared__ u16 h_lds[64*HS2];
  __shared__ float b1s[128];
  __shared__ float b2s[64];

  const int t = threadIdx.x, lane = t & 63, wv = t >> 6;
  const int cl = lane & 15;
  const int row16 = wv*16 + cl;
  const int g8 = (lane >> 4) * 8;
  const int orow = wv*16 + (lane >> 4)*4;

  for (int i = t; i < 4*8*64*8; i += 256) {
    int j = i & 7, l = (i >> 3) & 63, nt = (i >> 9) & 7, kb = i >> 12;
    w1f[i] = f2bf(w1n[(kb*32 + (l >> 4)*8 + j)*128 + 8*(l & 15) + nt]);
  }
  for (int i = t; i < 4*4*64*8; i += 256) {
    int j = i & 7, l = (i >> 3) & 63, nt = (i >> 9) & 3, kb = i >> 11;
    w2f[i] = f2bf(w2n[(kb*32 + (l >> 4)*8 + j)*64 + 4*(l & 15) + nt]);
  }
  if (t < 128) b1s[t] = b1n[t];
  if (t < 64)  b2s[t] = b2n[t];

  for (int tile = blockIdx.x; tile < NT_NODE; tile += gridDim.x) {
    const int n0 = tile * 64;
    __syncthreads();                    // protect a_lds/h_lds reuse
    {
      const int nd = t >> 2, q = t & 3;
      const int gn = n0 + nd;
      u16* arow = a_lds + nd*HS2;
      if (gn < NN) {
        float4 vf = ((const float4*)(node_feat + (size_t)gn*64 + q*16))[0];
        float4 vf2 = ((const float4*)(node_feat + (size_t)gn*64 + q*16))[1];
        float4 vf3 = ((const float4*)(node_feat + (size_t)gn*64 + q*16))[2];
        float4 vf4 = ((const float4*)(node_feat + (size_t)gn*64 + q*16))[3];
        uint4 qa = { pk2bf(vf.x, vf.y),  pk2bf(vf.z, vf.w),
                     pk2bf(vf2.x, vf2.y), pk2bf(vf2.z, vf2.w) };
        uint4 qb = { pk2bf(vf3.x, vf3.y), pk2bf(vf3.z, vf3.w),
                     pk2bf(vf4.x, vf4.y), pk2bf(vf4.z, vf4.w) };
        *(uint4*)(arow + q*16) = qa;
        *(uint4*)(arow + q*16 + 8) = qb;
        float4 vm = ((const float4*)(msg_tot + (size_t)gn*64 + q*16))[0];
        float4 vm2 = ((const float4*)(msg_tot + (size_t)gn*64 + q*16))[1];
        float4 vm3 = ((const float4*)(msg_tot + (size_t)gn*64 + q*16))[2];
        float4 vm4 = ((const float4*)(msg_tot + (size_t)gn*64 + q*16))[3];
        uint4 qc = { pk2bf(vm.x, vm.y),  pk2bf(vm.z, vm.w),
                     pk2bf(vm2.x, vm2.y), pk2bf(vm2.z, vm2.w) };
        uint4 qd = { pk2bf(vm3.x, vm3.y), pk2bf(vm3.z, vm3.w),
                     pk2bf(vm4.x, vm4.y), pk2bf(vm4.z, vm4.w) };
        *(uint4*)(arow + 64 + q*16) = qc;
        *(uint4*)(arow + 64 + q*16 + 8) = qd;
      } else {
        uint4 z = {0,0,0,0};
        *(uint4*)(arow + q*16) = z;  *(uint4*)(arow + q*16 + 8) = z;
        *(uint4*)(arow + 64 + q*16) = z; *(uint4*)(arow + 64 + q*16 + 8) = z;
      }
    }
    __syncthreads();
    {
      f32x4 acc[8];
      #pragma unroll
      for (int nt = 0; nt < 8; ++nt) acc[nt] = (f32x4){0.f,0.f,0.f,0.f};
      #pragma unroll
      for (int kb = 0; kb < 4; ++kb) {
        bf16x8 af = *(const bf16x8*)(a_lds + row16*HS2 + kb*32 + g8);
        #pragma unroll
        for (int nt = 0; nt < 8; ++nt) {
          bf16x8 bfv = *(const bf16x8*)(w1f + ((kb*8 + nt)*64 + lane)*8);
          acc[nt] = __builtin_amdgcn_mfma_f32_16x16x32_bf16(af, bfv, acc[nt], 0, 0, 0);
        }
      }
      // lane holds h[row][8*cl + nt]; bias col = 8*cl+nt
      #pragma unroll
      for (int r = 0; r < 4; ++r) {
        uint4 q;
        q.x = pk2bf(silu_f(acc[0][r] + b1s[8*cl+0]), silu_f(acc[1][r] + b1s[8*cl+1]));
        q.y = pk2bf(silu_f(acc[2][r] + b1s[8*cl+2]), silu_f(acc[3][r] + b1s[8*cl+3]));
        q.z = pk2bf(silu_f(acc[4][r] + b1s[8*cl+4]), silu_f(acc[5][r] + b1s[8*cl+5]));
        q.w = pk2bf(silu_f(acc[6][r] + b1s[8*cl+6]), silu_f(acc[7][r] + b1s[8*cl+7]));
        *(uint4*)(h_lds + (orow + r)*HS2 + 8*cl) = q;
      }
    }
    __syncthreads();
    {
      f32x4 acc[4];
      #pragma unroll
      for (int nt = 0; nt < 4; ++nt) acc[nt] = (f32x4){0.f,0.f,0.f,0.f};
      #pragma unroll
      for (int kb = 0; kb < 4; ++kb) {
        bf16x8 af = *(const bf16x8*)(h_lds + row16*HS2 + kb*32 + g8);
        #pragma unroll
        for (int nt = 0; nt < 4; ++nt) {
          bf16x8 bfv = *(const bf16x8*)(w2f + ((kb*4 + nt)*64 + lane)*8);
          acc[nt] = __builtin_amdgcn_mfma_f32_16x16x32_bf16(af, bfv, acc[nt], 0, 0, 0);
        }
      }
      // lane holds out[row][4*cl + nt] -> float4 store
      #pragma unroll
      for (int r = 0; r < 4; ++r) {
        int row = orow + r, gn = n0 + row;
        if (gn < NN) {
          float4 base = *(const float4*)(node_feat + (size_t)gn*64 + 4*cl);
          float4 o;
          o.x = acc[0][r] + b2s[4*cl+0] + base.x;
          o.y = acc[1][r] + b2s[4*cl+1] + base.y;
          o.z = acc[2][r] + b2s[4*cl+2] + base.z;
          o.w = acc[3][r] + b2s[4*cl+3] + base.w;
          *(float4*)(out_feat + (size_t)gn*64 + 4*cl) = o;
        }
      }
    }
  }
}

extern "C" void kernel_launch(void* const* d_in, const int* in_sizes, int n_in,
                              void* d_out, int out_size, void* d_ws, size_t ws_size,
                              hipStream_t stream) {
  (void)in_sizes; (void)n_in; (void)out_size;
  const float* node_feat = (const float*)d_in[0];
  const float* coord     = (const float*)d_in[1];
  const float* edge_feat = (const float*)d_in[2];
  const int*   eidx      = (const int*)d_in[3];
  const float* w1_msg    = (const float*)d_in[4];
  const float* w2_msg    = (const float*)d_in[5];
  const float* w1_mov    = (const float*)d_in[6];
  const float* w2_mov    = (const float*)d_in[7];
  const float* w1n       = (const float*)d_in[9];
  const float* b1n       = (const float*)d_in[10];
  const float* w2n       = (const float*)d_in[11];
  const float* b2n       = (const float*)d_in[12];

  float* out_feat  = (float*)d_out;
  float* out_coord = out_feat + (size_t)NN * 64;

  // workspace layout
  int*   count   = (int*)d_ws;                          // 50048
  int*   cursor  = count + 50048;                       // 50048
  int*   bsum    = cursor + 50048;                      // 1024
  int*   boff    = bsum + 1024;                         // 1024
  float* msg_tot = (float*)(boff + 1024);               // 3.2M floats
  int*   eid     = (int*)(msg_tot + (size_t)NN*64);     // 1.6M ints
  u16*   nf16    = (u16*)(eid + E_TOT);                 // 3.2M u16 (6.4 MB)
  const size_t need16 = (size_t)((char*)(nf16 + (size_t)NN*64) - (char*)d_ws);
  const int use16 = ws_size >= need16 ? 1 : 0;

  hipMemsetAsync(count, 0, NN * sizeof(int), stream);
  hipMemsetAsync(msg_tot, 0, (size_t)NN * 64 * sizeof(float), stream);
  hipMemcpyAsync(out_coord, coord, (size_t)NN * 3 * sizeof(float),
                 hipMemcpyDeviceToDevice, stream);
  if (use16) cvt_k<<<2048, 256, 0, stream>>>(node_feat, nf16, NN*64/4);
  hist_k<<<2048, 256, 0, stream>>>(eidx, count);
  scanA_k<<<NB, 256, 0, stream>>>(count, bsum);
  scanB_k<<<1, 256, 0, stream>>>(bsum, boff);
  scanC_k<<<NB, 256, 0, stream>>>(count, boff, cursor);
  scatter_k<<<2048, 256, 0, stream>>>(eidx, cursor, eid);
  egnn_edge<<<256, 512, 0, stream>>>(node_feat, coord, edge_feat, eidx, eid,
      w1_msg, w2_msg, w1_mov, w2_mov, nf16, use16, msg_tot, out_coord);
  egnn_node<<<256, 256, 0, stream>>>(node_feat, msg_tot,
      w1n, b1n, w2n, b2n, out_feat);
}